// Round 2
// baseline (937.664 us; speedup 1.0000x reference)
//
#include <hip/hip_runtime.h>
#include <hip/hip_bf16.h>
#include <math.h>

#define HIDDEN 4096
#define NH 32
#define NKV 8
#define HD 128
#define QKVC 6144   // 4096 (Q) + 1024 (K) + 1024 (V)

using f32x4  = __attribute__((ext_vector_type(4))) float;
using frag_ab = __attribute__((ext_vector_type(8))) short;

__device__ __forceinline__ short f2bf(float x){
  __hip_bfloat16 h = __float2bfloat16(x);
  return *reinterpret_cast<short*>(&h);
}
__device__ __forceinline__ float bf2f(short s){
  __hip_bfloat16 h = *reinterpret_cast<__hip_bfloat16*>(&s);
  return __bfloat162float(h);
}

__device__ __forceinline__ void load_lds16(const void* g, void* l){
  __builtin_amdgcn_global_load_lds(
      (const __attribute__((address_space(1))) unsigned*)g,
      (__attribute__((address_space(3))) unsigned*)l, 16, 0, 0);
}

// ---------------- fp32 -> bf16 convert (vectorized) ----------------
__global__ __launch_bounds__(256) void k_cvt(const float* __restrict__ X, short* __restrict__ Y, int n4){
  int i = blockIdx.x*256 + threadIdx.x;
  if (i >= n4) return;
  float4 v = reinterpret_cast<const float4*>(X)[i];
  short4 o;
  o.x = f2bf(v.x); o.y = f2bf(v.y); o.z = f2bf(v.z); o.w = f2bf(v.w);
  reinterpret_cast<short4*>(Y)[i] = o;
}

// ------------- W (K x N, fp32) -> WT (N x K, bf16) transpose -------------
__global__ __launch_bounds__(256) void k_transpose(const float* __restrict__ W, short* __restrict__ WT,
                                                   int K, int N){
  __shared__ float tile[32][33];
  int n0 = blockIdx.x*32, k0 = blockIdx.y*32;
  int tx = threadIdx.x & 31, ty = threadIdx.x >> 5;  // 32 x 8
  #pragma unroll
  for (int i=0;i<4;i++) tile[ty+i*8][tx] = W[(size_t)(k0+ty+i*8)*N + n0+tx];
  __syncthreads();
  #pragma unroll
  for (int i=0;i<4;i++) WT[(size_t)(n0+ty+i*8)*K + k0+tx] = f2bf(tile[tx][ty+i*8]);
}

// ------------- bf16 GEMM: C[M][N] = A[M][K] * BT[N][K]^T (m97 structure) -------------
template<typename OutT>
__global__ __launch_bounds__(256) void k_gemm_bt(const short* __restrict__ A, const short* __restrict__ BT,
                                                 OutT* __restrict__ C, int M, int N, int K){
  __shared__ __align__(16) short As[128*64];
  __shared__ __align__(16) short Bs[128*64];
  const int brow = blockIdx.x*128, bcol = blockIdx.y*128;
  const int t = threadIdx.x, lane = t & 63, wid = t >> 6;
  const int wm = wid >> 1, wn = wid & 1;
  const int l15 = lane & 15, lg = lane >> 4;
  f32x4 acc[4][4] = {};
  const int nk = K >> 6;
  for (int kt = 0; kt < nk; ++kt){
    __syncthreads();
    #pragma unroll
    for (int i=0;i<4;i++){
      int slot = t + i*256;            // 1024 slots of 16B per tile
      int row  = slot >> 3;            // 128 rows
      int col  = (slot & 7) << 3;      // 8 chunks of 8 bf16 per 64-wide row
      load_lds16(A  + (size_t)(brow+row)*K + (size_t)kt*64 + col, &As[slot*8]);
      load_lds16(BT + (size_t)(bcol+row)*K + (size_t)kt*64 + col, &Bs[slot*8]);
    }
    __syncthreads();
    #pragma unroll
    for (int ks=0; ks<2; ++ks){
      frag_ab a[4], b[4];
      #pragma unroll
      for (int mi=0;mi<4;mi++) a[mi] = *(const frag_ab*)&As[(wm*64+mi*16+l15)*64 + ks*32 + lg*8];
      #pragma unroll
      for (int ni=0;ni<4;ni++) b[ni] = *(const frag_ab*)&Bs[(wn*64+ni*16+l15)*64 + ks*32 + lg*8];
      #pragma unroll
      for (int mi=0;mi<4;mi++)
        #pragma unroll
        for (int ni=0;ni<4;ni++)
          acc[mi][ni] = __builtin_amdgcn_mfma_f32_16x16x32_bf16(a[mi], b[ni], acc[mi][ni], 0, 0, 0);
    }
  }
  #pragma unroll
  for (int mi=0;mi<4;mi++)
    #pragma unroll
    for (int ni=0;ni<4;ni++)
      #pragma unroll
      for (int r=0;r<4;r++){
        size_t row = brow + wm*64 + mi*16 + lg*4 + r;
        size_t col = bcol + wn*64 + ni*16 + l15;
        float v = acc[mi][ni][r];
        if constexpr (sizeof(OutT) == 4) C[row*(size_t)N + col] = v;
        else                             C[row*(size_t)N + col] = f2bf(v);
      }
}

// ---------------- RoPE in-place on QKV (Q heads + K heads) ----------------
__global__ __launch_bounds__(256) void k_rope(short* __restrict__ QKV, const int* __restrict__ pos){
  int idx = blockIdx.x*256 + threadIdx.x;     // total = 2048 * 40 * 64
  int j   = idx & 63;
  int hh  = (idx >> 6) % 40;
  int row = (idx >> 6) / 40;
  int colbase = hh < NH ? hh*HD : HIDDEN + (hh-NH)*HD;
  size_t base = (size_t)row*QKVC + colbase;
  float x1 = bf2f(QKV[base + j]), x2 = bf2f(QKV[base + j + 64]);
  float ang = (float)pos[row] * exp2f(-(float)j * 0.2076205059304601f); // log2(1e4)/64
  float sn, cs; sincosf(ang, &sn, &cs);
  QKV[base + j]      = f2bf(x1*cs - x2*sn);
  QKV[base + j + 64] = f2bf(x2*cs + x1*sn);
}

// ---------------- flash attention: 1 block = (64 q rows, 1 head) ----------------
__global__ __launch_bounds__(256) void k_attn(const short* __restrict__ QKV, short* __restrict__ Attn){
  const int qt = blockIdx.x, h = blockIdx.y, kvh = h >> 2;
  const int t = threadIdx.x, lane = t & 63, w = t >> 6;
  const int l15 = lane & 15, lg = lane >> 4;
  __shared__ __align__(16) short Ks[32*128];      // K tile, XOR-swizzled rows
  __shared__ __align__(16) short Vt[128*40];      // V^T, padded stride 40
  __shared__ __align__(16) short Ps[4][16*48];    // per-wave P tile, stride 48 (16B aligned)

  // Q fragments (16 rows per wave) straight from global, held in registers
  frag_ab aq[4];
  {
    const short* qrow = QKV + (size_t)(qt*64 + w*16 + l15)*QKVC + h*HD;
    #pragma unroll
    for (int ks=0;ks<4;ks++) aq[ks] = *(const frag_ab*)&qrow[ks*32 + lg*8];
  }
  float mrow[4], lrow[4];
  #pragma unroll
  for (int r=0;r<4;r++){ mrow[r] = -INFINITY; lrow[r] = 0.f; }
  f32x4 o[8] = {};
  const float SC = 0.08838834764831845f;  // 1/sqrt(128)
  const int nkv = 2*qt + 2;
  for (int kt = 0; kt < nkv; ++kt){
    __syncthreads();
    // stage K (swizzled) + V (transposed)
    #pragma unroll
    for (int i=0;i<2;i++){
      int slot = t + i*256;          // 512 chunks of 8 bf16
      int row  = slot >> 4;          // 0..31
      int d8   = (slot & 15) << 3;   // 0..120
      size_t gk = (size_t)(kt*32 + row)*QKVC + HIDDEN + kvh*HD + d8;
      uint4 kk = *(const uint4*)&QKV[gk];
      *(uint4*)&Ks[row*128 + (d8 ^ ((row & 7) << 3))] = kk;
      uint4 vv = *(const uint4*)&QKV[gk + 1024];
      short tmp[8]; *(uint4*)tmp = vv;
      #pragma unroll
      for (int jj=0;jj<8;jj++) Vt[(d8+jj)*40 + row] = tmp[jj];
    }
    __syncthreads();
    // S = Q K^T  (two 16-col fragments)
    f32x4 sc[2] = {};
    #pragma unroll
    for (int ks=0;ks<4;ks++){
      int c = ks*32 + lg*8;
      frag_ab b0 = *(const frag_ab*)&Ks[l15*128       + (c ^ ((l15 & 7) << 3))];
      frag_ab b1 = *(const frag_ab*)&Ks[(16+l15)*128  + (c ^ ((l15 & 7) << 3))];
      sc[0] = __builtin_amdgcn_mfma_f32_16x16x32_bf16(aq[ks], b0, sc[0], 0, 0, 0);
      sc[1] = __builtin_amdgcn_mfma_f32_16x16x32_bf16(aq[ks], b1, sc[1], 0, 0, 0);
    }
    // mask + scale + online softmax (row r lives at lane-group lg, reg r)
    float p0[4], p1[4];
    #pragma unroll
    for (int r=0;r<4;r++){
      int rowg = qt*64 + w*16 + lg*4 + r;
      int c0 = kt*32 + l15, c1 = c0 + 16;
      float v0 = sc[0][r]*SC, v1 = sc[1][r]*SC;
      if (c0 > rowg) v0 = -1e30f;
      if (c1 > rowg) v1 = -1e30f;
      float pm = fmaxf(v0, v1);
      pm = fmaxf(pm, __shfl_xor(pm, 1));
      pm = fmaxf(pm, __shfl_xor(pm, 2));
      pm = fmaxf(pm, __shfl_xor(pm, 4));
      pm = fmaxf(pm, __shfl_xor(pm, 8));
      float mn = fmaxf(mrow[r], pm);
      float f  = expf(mrow[r] - mn);
      mrow[r] = mn;
      float e0 = expf(v0 - mn), e1 = expf(v1 - mn);
      float ps = e0 + e1;
      ps += __shfl_xor(ps, 1); ps += __shfl_xor(ps, 2);
      ps += __shfl_xor(ps, 4); ps += __shfl_xor(ps, 8);
      lrow[r] = lrow[r]*f + ps;
      p0[r] = e0; p1[r] = e1;
      #pragma unroll
      for (int df=0;df<8;df++) o[df][r] *= f;
    }
    // P -> LDS (per-wave, no cross-wave sync needed)
    #pragma unroll
    for (int r=0;r<4;r++){
      Ps[w][(lg*4+r)*48 + l15]      = f2bf(p0[r]);
      Ps[w][(lg*4+r)*48 + 16 + l15] = f2bf(p1[r]);
    }
    // O += P V
    frag_ab pa = *(const frag_ab*)&Ps[w][l15*48 + lg*8];
    #pragma unroll
    for (int df=0;df<8;df++){
      frag_ab vb = *(const frag_ab*)&Vt[(df*16+l15)*40 + lg*8];
      o[df] = __builtin_amdgcn_mfma_f32_16x16x32_bf16(pa, vb, o[df], 0, 0, 0);
    }
  }
  // epilogue: O / l -> Attn[row][h*128+d]
  #pragma unroll
  for (int df=0;df<8;df++)
    #pragma unroll
    for (int r=0;r<4;r++){
      size_t row = qt*64 + w*16 + lg*4 + r;
      size_t col = (size_t)h*HD + df*16 + l15;
      Attn[row*HIDDEN + col] = f2bf(o[df][r] / lrow[r]);
    }
}

// ---------------- launch ----------------
extern "C" void kernel_launch(void* const* d_in, const int* in_sizes, int n_in,
                              void* d_out, int out_size, void* d_ws, size_t ws_size,
                              hipStream_t stream) {
  const float* H  = (const float*)d_in[0];
  const int*  pos = (const int*)  d_in[1];
  const float* Wq = (const float*)d_in[2];
  const float* Wk = (const float*)d_in[3];
  const float* Wv = (const float*)d_in[4];
  const float* Wo = (const float*)d_in[5];
  float* out = (float*)d_out;

  char* ws = (char*)d_ws;
  // ws layout (total ~142.6 MB)
  short* WT   = (short*)(ws);                       // [6144][4096] bf16 (Wq^T | Wk^T | Wv^T)
  short* WoT  = (short*)(ws + 50331648);            // [4096][4096] bf16
  short* Hb   = (short*)(ws + 83886080);            // [2048][4096] bf16
  short* QKV  = (short*)(ws + 100663296);           // [2048][6144] bf16
  short* Attn = (short*)(ws + 125829120);           // [2048][4096] bf16

  k_cvt<<<8192, 256, 0, stream>>>(H, Hb, 2097152);
  k_transpose<<<dim3(128,128), 256, 0, stream>>>(Wq, WT,                        4096, 4096);
  k_transpose<<<dim3( 32,128), 256, 0, stream>>>(Wk, WT + (size_t)4096*4096,    4096, 1024);
  k_transpose<<<dim3( 32,128), 256, 0, stream>>>(Wv, WT + (size_t)5120*4096,    4096, 1024);
  k_transpose<<<dim3(128,128), 256, 0, stream>>>(Wo, WoT,                       4096, 4096);

  k_gemm_bt<short><<<dim3(16,48), 256, 0, stream>>>(Hb, WT, QKV, 2048, 6144, 4096);
  k_rope<<<20480, 256, 0, stream>>>(QKV, pos);
  k_attn<<<dim3(32,32), 256, 0, stream>>>(QKV, Attn);
  k_gemm_bt<float><<<dim3(16,32), 256, 0, stream>>>(Attn, WoT, out, 2048, 4096, 4096);
}

// Round 3
// 629.705 us; speedup vs baseline: 1.4891x; 1.4891x over previous
//
#include <hip/hip_runtime.h>
#include <hip/hip_bf16.h>
#include <math.h>

#define HIDDEN 4096
#define NH 32
#define NKV 8
#define HD 128
#define QKVC 6144   // 4096 (Q) + 1024 (K) + 1024 (V)

using f32x4  = __attribute__((ext_vector_type(4))) float;
using frag_ab = __attribute__((ext_vector_type(8))) short;

__device__ __forceinline__ short f2bf(float x){
  __hip_bfloat16 h = __float2bfloat16(x);
  return *reinterpret_cast<short*>(&h);
}
__device__ __forceinline__ float bf2f(short s){
  __hip_bfloat16 h = *reinterpret_cast<__hip_bfloat16*>(&s);
  return __bfloat162float(h);
}

__device__ __forceinline__ void load_lds16(const void* g, void* l){
  __builtin_amdgcn_global_load_lds(
      (const __attribute__((address_space(1))) unsigned*)g,
      (__attribute__((address_space(3))) unsigned*)l, 16, 0, 0);
}

// ---------------- fp32 -> bf16 convert (vectorized) ----------------
__global__ __launch_bounds__(256) void k_cvt(const float* __restrict__ X, short* __restrict__ Y, int n4){
  int i = blockIdx.x*256 + threadIdx.x;
  if (i >= n4) return;
  float4 v = reinterpret_cast<const float4*>(X)[i];
  short4 o;
  o.x = f2bf(v.x); o.y = f2bf(v.y); o.z = f2bf(v.z); o.w = f2bf(v.w);
  reinterpret_cast<short4*>(Y)[i] = o;
}

// ------------- W (K x N, fp32) -> WT (N x K, bf16) transpose -------------
__global__ __launch_bounds__(256) void k_transpose(const float* __restrict__ W, short* __restrict__ WT,
                                                   int K, int N){
  __shared__ float tile[32][33];
  int n0 = blockIdx.x*32, k0 = blockIdx.y*32;
  int tx = threadIdx.x & 31, ty = threadIdx.x >> 5;  // 32 x 8
  #pragma unroll
  for (int i=0;i<4;i++) tile[ty+i*8][tx] = W[(size_t)(k0+ty+i*8)*N + n0+tx];
  __syncthreads();
  #pragma unroll
  for (int i=0;i<4;i++) WT[(size_t)(n0+ty+i*8)*K + k0+tx] = f2bf(tile[tx][ty+i*8]);
}

// ------------- V block of QKV -> VT [1024 dg][2048 s] bf16 -------------
__global__ __launch_bounds__(256) void k_transpose_v(const short* __restrict__ QKV, short* __restrict__ VT){
  __shared__ short tile[32][40];
  int s0 = blockIdx.x*32, d0 = blockIdx.y*32;   // grid (64, 32)
  int tx = threadIdx.x & 31, ty = threadIdx.x >> 5;
  #pragma unroll
  for (int i=0;i<4;i++) tile[ty+i*8][tx] = QKV[(size_t)(s0+ty+i*8)*QKVC + 5120 + d0+tx];
  __syncthreads();
  #pragma unroll
  for (int i=0;i<4;i++) VT[(size_t)(d0+ty+i*8)*2048 + s0+tx] = tile[tx][ty+i*8];
}

// ------------- bf16 GEMM: C[M][N] = A[M][K] * BT[N][K]^T (m97 structure) -------------
template<typename OutT>
__global__ __launch_bounds__(256) void k_gemm_bt(const short* __restrict__ A, const short* __restrict__ BT,
                                                 OutT* __restrict__ C, int M, int N, int K){
  __shared__ __align__(16) short As[128*64];
  __shared__ __align__(16) short Bs[128*64];
  const int brow = blockIdx.x*128, bcol = blockIdx.y*128;
  const int t = threadIdx.x, lane = t & 63, wid = t >> 6;
  const int wm = wid >> 1, wn = wid & 1;
  const int l15 = lane & 15, lg = lane >> 4;
  f32x4 acc[4][4] = {};
  const int nk = K >> 6;
  for (int kt = 0; kt < nk; ++kt){
    __syncthreads();
    #pragma unroll
    for (int i=0;i<4;i++){
      int slot = t + i*256;            // 1024 slots of 16B per tile
      int row  = slot >> 3;            // 128 rows
      int col  = (slot & 7) << 3;      // 8 chunks of 8 bf16 per 64-wide row
      load_lds16(A  + (size_t)(brow+row)*K + (size_t)kt*64 + col, &As[slot*8]);
      load_lds16(BT + (size_t)(bcol+row)*K + (size_t)kt*64 + col, &Bs[slot*8]);
    }
    __syncthreads();
    #pragma unroll
    for (int ks=0; ks<2; ++ks){
      frag_ab a[4], b[4];
      #pragma unroll
      for (int mi=0;mi<4;mi++) a[mi] = *(const frag_ab*)&As[(wm*64+mi*16+l15)*64 + ks*32 + lg*8];
      #pragma unroll
      for (int ni=0;ni<4;ni++) b[ni] = *(const frag_ab*)&Bs[(wn*64+ni*16+l15)*64 + ks*32 + lg*8];
      #pragma unroll
      for (int mi=0;mi<4;mi++)
        #pragma unroll
        for (int ni=0;ni<4;ni++)
          acc[mi][ni] = __builtin_amdgcn_mfma_f32_16x16x32_bf16(a[mi], b[ni], acc[mi][ni], 0, 0, 0);
    }
  }
  #pragma unroll
  for (int mi=0;mi<4;mi++)
    #pragma unroll
    for (int ni=0;ni<4;ni++)
      #pragma unroll
      for (int r=0;r<4;r++){
        size_t row = brow + wm*64 + mi*16 + lg*4 + r;
        size_t col = bcol + wn*64 + ni*16 + l15;
        float v = acc[mi][ni][r];
        if constexpr (sizeof(OutT) == 4) C[row*(size_t)N + col] = v;
        else                             C[row*(size_t)N + col] = f2bf(v);
      }
}

// ---------------- RoPE in-place on QKV (Q heads + K heads) ----------------
__global__ __launch_bounds__(256) void k_rope(short* __restrict__ QKV, const int* __restrict__ pos){
  int idx = blockIdx.x*256 + threadIdx.x;     // total = 2048 * 40 * 64
  int j   = idx & 63;
  int hh  = (idx >> 6) % 40;
  int row = (idx >> 6) / 40;
  int colbase = hh < NH ? hh*HD : HIDDEN + (hh-NH)*HD;
  size_t base = (size_t)row*QKVC + colbase;
  float x1 = bf2f(QKV[base + j]), x2 = bf2f(QKV[base + j + 64]);
  float ang = (float)pos[row] * exp2f(-(float)j * 0.2076205059304601f); // log2(1e4)/64
  float sn, cs; sincosf(ang, &sn, &cs);
  QKV[base + j]      = f2bf(x1*cs - x2*sn);
  QKV[base + j + 64] = f2bf(x2*cs + x1*sn);
}

// ---------------- flash attention ----------------
// block = (pair of q-tiles {qt, 31-qt}, 1 head) -> uniform 66 kv-tiles per block
__global__ __launch_bounds__(256) void k_attn(const short* __restrict__ QKV, const short* __restrict__ VT,
                                              short* __restrict__ Attn){
  const int pairI = blockIdx.x, h = blockIdx.y, kvh = h >> 2;
  const int t = threadIdx.x, lane = t & 63, w = t >> 6;
  const int l15 = lane & 15, lg = lane >> 4;
  __shared__ __align__(16) short Ks[32*128];      // K tile, XOR-swizzled (write via pre-swizzled src)
  __shared__ __align__(16) short Vs[128*40];      // V^T tile [d][k], padded stride 40
  __shared__ __align__(16) short Ps[4][16*40];    // per-wave P tile, stride 40

  const float SC = 0.08838834764831845f;  // 1/sqrt(128)

  for (int half = 0; half < 2; ++half){
    const int qt = half ? (31 - pairI) : pairI;
    // Q fragments (16 rows per wave) from global, held in registers
    frag_ab aq[4];
    {
      const short* qrow = QKV + (size_t)(qt*64 + w*16 + l15)*QKVC + h*HD;
      #pragma unroll
      for (int ks=0;ks<4;ks++) aq[ks] = *(const frag_ab*)&qrow[ks*32 + lg*8];
    }
    float mrow[4], lrow[4];
    #pragma unroll
    for (int r=0;r<4;r++){ mrow[r] = -INFINITY; lrow[r] = 0.f; }
    f32x4 o[8] = {};
    const int nkv = 2*qt + 2;
    for (int kt = 0; kt < nkv; ++kt){
      __syncthreads();
      // stage K via global_load_lds, source pre-swizzled so LDS holds row*128 + (c ^ ((row&7)<<3))
      #pragma unroll
      for (int i=0;i<2;i++){
        int s = t + i*256;             // 512 chunks of 16B
        int row = s >> 4;              // 0..31
        int c8  = (s & 15) << 3;       // 0..120
        int csw = c8 ^ ((row & 7) << 3);
        load_lds16(QKV + (size_t)(kt*32 + row)*QKVC + HIDDEN + kvh*HD + csw, &Ks[s*8]);
      }
      // stage V^T tile from pre-transposed global VT (vectorized, padded stride)
      #pragma unroll
      for (int i=0;i<2;i++){
        int s = t + i*256;             // 512 chunks of 8 shorts
        int d  = s >> 2;               // 0..127
        int k8 = (s & 3) << 3;         // 0,8,16,24
        uint4 vv = *(const uint4*)&VT[(size_t)(kvh*HD + d)*2048 + kt*32 + k8];
        *(uint4*)&Vs[d*40 + k8] = vv;
      }
      __syncthreads();
      // S = Q K^T  (two 16-col fragments)
      f32x4 sc[2] = {};
      #pragma unroll
      for (int ks=0;ks<4;ks++){
        int c = ks*32 + lg*8;
        frag_ab b0 = *(const frag_ab*)&Ks[l15*128      + (c ^ ((l15 & 7) << 3))];
        frag_ab b1 = *(const frag_ab*)&Ks[(16+l15)*128 + (c ^ ((l15 & 7) << 3))];
        sc[0] = __builtin_amdgcn_mfma_f32_16x16x32_bf16(aq[ks], b0, sc[0], 0, 0, 0);
        sc[1] = __builtin_amdgcn_mfma_f32_16x16x32_bf16(aq[ks], b1, sc[1], 0, 0, 0);
      }
      // mask + scale + online softmax (row r at lane-group lg, reg r)
      float p0[4], p1[4];
      #pragma unroll
      for (int r=0;r<4;r++){
        int rowg = qt*64 + w*16 + lg*4 + r;
        int c0 = kt*32 + l15, c1 = c0 + 16;
        float v0 = sc[0][r]*SC, v1 = sc[1][r]*SC;
        if (c0 > rowg) v0 = -1e30f;
        if (c1 > rowg) v1 = -1e30f;
        float pm = fmaxf(v0, v1);
        pm = fmaxf(pm, __shfl_xor(pm, 1));
        pm = fmaxf(pm, __shfl_xor(pm, 2));
        pm = fmaxf(pm, __shfl_xor(pm, 4));
        pm = fmaxf(pm, __shfl_xor(pm, 8));
        float mn = fmaxf(mrow[r], pm);
        float f  = __expf(mrow[r] - mn);
        mrow[r] = mn;
        float e0 = __expf(v0 - mn), e1 = __expf(v1 - mn);
        float ps = e0 + e1;
        ps += __shfl_xor(ps, 1); ps += __shfl_xor(ps, 2);
        ps += __shfl_xor(ps, 4); ps += __shfl_xor(ps, 8);
        lrow[r] = lrow[r]*f + ps;
        p0[r] = e0; p1[r] = e1;
        #pragma unroll
        for (int df=0;df<8;df++) o[df][r] *= f;
      }
      // P -> LDS (per-wave region; no cross-wave sync needed)
      #pragma unroll
      for (int r=0;r<4;r++){
        Ps[w][(lg*4+r)*40 + l15]      = f2bf(p0[r]);
        Ps[w][(lg*4+r)*40 + 16 + l15] = f2bf(p1[r]);
      }
      // O += P V
      frag_ab pa = *(const frag_ab*)&Ps[w][l15*40 + lg*8];
      #pragma unroll
      for (int df=0;df<8;df++){
        frag_ab vb = *(const frag_ab*)&Vs[(df*16+l15)*40 + lg*8];
        o[df] = __builtin_amdgcn_mfma_f32_16x16x32_bf16(pa, vb, o[df], 0, 0, 0);
      }
    }
    // epilogue: O / l -> Attn[row][h*128+d]
    #pragma unroll
    for (int df=0;df<8;df++)
      #pragma unroll
      for (int r=0;r<4;r++){
        size_t row = qt*64 + w*16 + lg*4 + r;
        size_t col = (size_t)h*HD + df*16 + l15;
        Attn[row*HIDDEN + col] = f2bf(o[df][r] / lrow[r]);
      }
  }
}

// ---------------- launch ----------------
extern "C" void kernel_launch(void* const* d_in, const int* in_sizes, int n_in,
                              void* d_out, int out_size, void* d_ws, size_t ws_size,
                              hipStream_t stream) {
  const float* H  = (const float*)d_in[0];
  const int*  pos = (const int*)  d_in[1];
  const float* Wq = (const float*)d_in[2];
  const float* Wk = (const float*)d_in[3];
  const float* Wv = (const float*)d_in[4];
  const float* Wo = (const float*)d_in[5];
  float* out = (float*)d_out;

  char* ws = (char*)d_ws;
  // ws layout (total ~142.6 MB)
  short* WT   = (short*)(ws);                       // [6144][4096] bf16 (Wq^T | Wk^T | Wv^T)
  short* WoT  = (short*)(ws + 50331648);            // [4096][4096] bf16
  short* Hb   = (short*)(ws + 83886080);            // [2048][4096] bf16 (dead after QKV GEMM)
  short* QKV  = (short*)(ws + 100663296);           // [2048][6144] bf16
  short* Attn = (short*)(ws + 125829120);           // [2048][4096] bf16
  short* VT   = Hb;                                 // [1024][2048] bf16 (reuses Hb slot, 4 MB)

  k_cvt<<<8192, 256, 0, stream>>>(H, Hb, 2097152);
  k_transpose<<<dim3(128,128), 256, 0, stream>>>(Wq, WT,                        4096, 4096);
  k_transpose<<<dim3( 32,128), 256, 0, stream>>>(Wk, WT + (size_t)4096*4096,    4096, 1024);
  k_transpose<<<dim3( 32,128), 256, 0, stream>>>(Wv, WT + (size_t)5120*4096,    4096, 1024);
  k_transpose<<<dim3(128,128), 256, 0, stream>>>(Wo, WoT,                       4096, 4096);

  k_gemm_bt<short><<<dim3(16,48), 256, 0, stream>>>(Hb, WT, QKV, 2048, 6144, 4096);
  k_rope<<<20480, 256, 0, stream>>>(QKV, pos);
  k_transpose_v<<<dim3(64,32), 256, 0, stream>>>(QKV, VT);
  k_attn<<<dim3(16,32), 256, 0, stream>>>(QKV, VT, Attn);
  k_gemm_bt<float><<<dim3(16,32), 256, 0, stream>>>(Attn, WoT, out, 2048, 4096, 4096);
}

// Round 4
// 595.278 us; speedup vs baseline: 1.5752x; 1.0578x over previous
//
#include <hip/hip_runtime.h>
#include <hip/hip_bf16.h>
#include <math.h>

#define HIDDEN 4096
#define NH 32
#define NKV 8
#define HD 128
#define QKVC 6144   // 4096 (Q) + 1024 (K) + 1024 (V)

using f32x4  = __attribute__((ext_vector_type(4))) float;
using frag_ab = __attribute__((ext_vector_type(8))) short;

__device__ __forceinline__ short f2bf(float x){
  __hip_bfloat16 h = __float2bfloat16(x);
  return *reinterpret_cast<short*>(&h);
}
__device__ __forceinline__ float bf2f(short s){
  __hip_bfloat16 h = *reinterpret_cast<__hip_bfloat16*>(&s);
  return __bfloat162float(h);
}

__device__ __forceinline__ void load_lds16(const void* g, void* l){
  __builtin_amdgcn_global_load_lds(
      (const __attribute__((address_space(1))) unsigned*)g,
      (__attribute__((address_space(3))) unsigned*)l, 16, 0, 0);
}

__device__ __forceinline__ void hard_barrier(){
  asm volatile("" ::: "memory");
  __builtin_amdgcn_s_barrier();
  asm volatile("" ::: "memory");
}

// ---------------- fp32 -> bf16 convert (vectorized) ----------------
__global__ __launch_bounds__(256) void k_cvt(const float* __restrict__ X, short* __restrict__ Y, int n4){
  int i = blockIdx.x*256 + threadIdx.x;
  if (i >= n4) return;
  float4 v = reinterpret_cast<const float4*>(X)[i];
  short4 o;
  o.x = f2bf(v.x); o.y = f2bf(v.y); o.z = f2bf(v.z); o.w = f2bf(v.w);
  reinterpret_cast<short4*>(Y)[i] = o;
}

// ------------- W (K x N, fp32) -> WT (N x K, bf16) transpose -------------
__global__ __launch_bounds__(256) void k_transpose(const float* __restrict__ W, short* __restrict__ WT,
                                                   int K, int N){
  __shared__ float tile[32][33];
  int n0 = blockIdx.x*32, k0 = blockIdx.y*32;
  int tx = threadIdx.x & 31, ty = threadIdx.x >> 5;  // 32 x 8
  #pragma unroll
  for (int i=0;i<4;i++) tile[ty+i*8][tx] = W[(size_t)(k0+ty+i*8)*N + n0+tx];
  __syncthreads();
  #pragma unroll
  for (int i=0;i<4;i++) WT[(size_t)(n0+ty+i*8)*K + k0+tx] = f2bf(tile[tx][ty+i*8]);
}

// ------------- V block of QKV -> VT [1024 dg][2048 s] bf16 -------------
__global__ __launch_bounds__(256) void k_transpose_v(const short* __restrict__ QKV, short* __restrict__ VT){
  __shared__ short tile[32][40];
  int s0 = blockIdx.x*32, d0 = blockIdx.y*32;   // grid (64, 32)
  int tx = threadIdx.x & 31, ty = threadIdx.x >> 5;
  #pragma unroll
  for (int i=0;i<4;i++) tile[ty+i*8][tx] = QKV[(size_t)(s0+ty+i*8)*QKVC + 5120 + d0+tx];
  __syncthreads();
  #pragma unroll
  for (int i=0;i<4;i++) VT[(size_t)(d0+ty+i*8)*2048 + s0+tx] = tile[tx][ty+i*8];
}

// ------------- pipelined bf16 GEMM: C[M][N] = A[M][K] * BT[N][K]^T -------------
// BM=256, BN=128, BK=32; 512 threads = 8 waves (4M x 2N); per-wave 64x64 output.
// 4-buffer LDS ring (96 KB); counted vmcnt (T3+T4); raw s_barrier; setprio (T5);
// bijective XCD swizzle (T1, grid % 8 == 0 guaranteed by caller).
template<typename OutT>
__global__ __launch_bounds__(512, 2) void k_gemm256(const short* __restrict__ A, const short* __restrict__ BT,
                                                    OutT* __restrict__ C, int M, int N, int K, int mt){
  __shared__ __align__(16) short L[49152];   // 4 buffers x (A 8192 + B 4096) shorts
  // XCD-aware block swizzle (gridDim.x % 8 == 0)
  const int nwg = gridDim.x, cpx = nwg >> 3;
  const int bid = blockIdx.x;
  const int swz = (bid & 7) * cpx + (bid >> 3);
  const int bx = swz % mt, by = swz / mt;
  const int brow = bx*256, bcol = by*128;
  const int tid = threadIdx.x, lane = tid & 63, wid = tid >> 6;
  const int wr = wid >> 1, wc = wid & 1;
  const int l15 = lane & 15, lg = lane >> 4;
  const int nk = K >> 5;

  // per-thread staging chunks: A = tid, tid+512 (1024 x 16B); B = tid (512 x 16B)
  const int ca0r = tid >> 2,        ca0c = (tid & 3) << 3;
  const int ca1r = (tid+512) >> 2,  ca1c = ((tid+512) & 3) << 3;
  const int cbr  = tid >> 2,        cbc  = (tid & 3) << 3;
  const short* Aponly = A + (size_t)brow*K;
  const short* Bponly = BT + (size_t)bcol*K;

  f32x4 acc[4][4] = {};

  #define STAGE(kt) do { \
    int _b = (kt) & 3; \
    load_lds16(Aponly + (size_t)ca0r*K + (kt)*32 + ca0c, &L[_b*12288 + tid*8]); \
    load_lds16(Aponly + (size_t)ca1r*K + (kt)*32 + ca1c, &L[_b*12288 + (tid+512)*8]); \
    load_lds16(Bponly + (size_t)cbr*K + (kt)*32 + cbc,  &L[_b*12288 + 8192 + tid*8]); \
  } while(0)

  // prologue: stage tiles 0,1,2 (9 loads/wave), drain to tile0 landed
  STAGE(0); STAGE(1); STAGE(2);
  asm volatile("s_waitcnt vmcnt(6)" ::: "memory");
  hard_barrier();

  for (int t = 0; t < nk; ++t){
    const int b = t & 3;
    const short* Ab = &L[b*12288];
    const short* Bb = &L[b*12288 + 8192];
    frag_ab af[4], bf[4];
    #pragma unroll
    for (int m=0;m<4;m++) af[m] = *(const frag_ab*)&Ab[(wr*64 + m*16 + l15)*32 + lg*8];
    #pragma unroll
    for (int n=0;n<4;n++) bf[n] = *(const frag_ab*)&Bb[(wc*64 + n*16 + l15)*32 + lg*8];
    if (t + 3 < nk) STAGE(t+3);
    hard_barrier();
    __builtin_amdgcn_s_setprio(1);
    #pragma unroll
    for (int m=0;m<4;m++)
      #pragma unroll
      for (int n=0;n<4;n++)
        acc[m][n] = __builtin_amdgcn_mfma_f32_16x16x32_bf16(af[m], bf[n], acc[m][n], 0, 0, 0);
    __builtin_amdgcn_s_setprio(0);
    // boundary: guarantee tile t+1 fully landed; keep t+2,t+3 in flight
    if (t < nk-3)       asm volatile("s_waitcnt vmcnt(6)" ::: "memory");
    else if (t == nk-3) asm volatile("s_waitcnt vmcnt(3)" ::: "memory");
    else                asm volatile("s_waitcnt vmcnt(0)" ::: "memory");
    hard_barrier();
  }
  #undef STAGE

  // epilogue
  #pragma unroll
  for (int m=0;m<4;m++)
    #pragma unroll
    for (int n=0;n<4;n++)
      #pragma unroll
      for (int r=0;r<4;r++){
        size_t row = brow + wr*64 + m*16 + lg*4 + r;
        size_t col = bcol + wc*64 + n*16 + l15;
        float v = acc[m][n][r];
        if constexpr (sizeof(OutT) == 4) C[row*(size_t)N + col] = v;
        else                             C[row*(size_t)N + col] = f2bf(v);
      }
}

// ---------------- RoPE in-place on QKV (Q heads + K heads) ----------------
__global__ __launch_bounds__(256) void k_rope(short* __restrict__ QKV, const int* __restrict__ pos){
  int idx = blockIdx.x*256 + threadIdx.x;     // total = 2048 * 40 * 64
  int j   = idx & 63;
  int hh  = (idx >> 6) % 40;
  int row = (idx >> 6) / 40;
  int colbase = hh < NH ? hh*HD : HIDDEN + (hh-NH)*HD;
  size_t base = (size_t)row*QKVC + colbase;
  float x1 = bf2f(QKV[base + j]), x2 = bf2f(QKV[base + j + 64]);
  float ang = (float)pos[row] * exp2f(-(float)j * 0.2076205059304601f); // log2(1e4)/64
  float sn, cs; sincosf(ang, &sn, &cs);
  QKV[base + j]      = f2bf(x1*cs - x2*sn);
  QKV[base + j + 64] = f2bf(x2*cs + x1*sn);
}

// ---------------- flash attention ----------------
// block = (pair of q-tiles {qt, 31-qt}, 1 head) -> uniform 66 kv-tiles per block
__global__ __launch_bounds__(256) void k_attn(const short* __restrict__ QKV, const short* __restrict__ VT,
                                              short* __restrict__ Attn){
  const int pairI = blockIdx.x, h = blockIdx.y, kvh = h >> 2;
  const int t = threadIdx.x, lane = t & 63, w = t >> 6;
  const int l15 = lane & 15, lg = lane >> 4;
  __shared__ __align__(16) short Ks[32*128];      // K tile, XOR-swizzled (write via pre-swizzled src)
  __shared__ __align__(16) short Vs[128*40];      // V^T tile [d][k], padded stride 40
  __shared__ __align__(16) short Ps[4][16*40];    // per-wave P tile, stride 40

  const float SC = 0.08838834764831845f;  // 1/sqrt(128)

  for (int half = 0; half < 2; ++half){
    const int qt = half ? (31 - pairI) : pairI;
    // Q fragments (16 rows per wave) from global, held in registers
    frag_ab aq[4];
    {
      const short* qrow = QKV + (size_t)(qt*64 + w*16 + l15)*QKVC + h*HD;
      #pragma unroll
      for (int ks=0;ks<4;ks++) aq[ks] = *(const frag_ab*)&qrow[ks*32 + lg*8];
    }
    float mrow[4], lrow[4];
    #pragma unroll
    for (int r=0;r<4;r++){ mrow[r] = -INFINITY; lrow[r] = 0.f; }
    f32x4 o[8] = {};
    const int nkv = 2*qt + 2;
    for (int kt = 0; kt < nkv; ++kt){
      __syncthreads();
      // stage K via global_load_lds, source pre-swizzled so LDS holds row*128 + (c ^ ((row&7)<<3))
      #pragma unroll
      for (int i=0;i<2;i++){
        int s = t + i*256;             // 512 chunks of 16B
        int row = s >> 4;              // 0..31
        int c8  = (s & 15) << 3;       // 0..120
        int csw = c8 ^ ((row & 7) << 3);
        load_lds16(QKV + (size_t)(kt*32 + row)*QKVC + HIDDEN + kvh*HD + csw, &Ks[s*8]);
      }
      // stage V^T tile from pre-transposed global VT (vectorized, padded stride)
      #pragma unroll
      for (int i=0;i<2;i++){
        int s = t + i*256;             // 512 chunks of 8 shorts
        int d  = s >> 2;               // 0..127
        int k8 = (s & 3) << 3;         // 0,8,16,24
        uint4 vv = *(const uint4*)&VT[(size_t)(kvh*HD + d)*2048 + kt*32 + k8];
        *(uint4*)&Vs[d*40 + k8] = vv;
      }
      __syncthreads();
      // S = Q K^T  (two 16-col fragments)
      f32x4 sc[2] = {};
      #pragma unroll
      for (int ks=0;ks<4;ks++){
        int c = ks*32 + lg*8;
        frag_ab b0 = *(const frag_ab*)&Ks[l15*128      + (c ^ ((l15 & 7) << 3))];
        frag_ab b1 = *(const frag_ab*)&Ks[(16+l15)*128 + (c ^ ((l15 & 7) << 3))];
        sc[0] = __builtin_amdgcn_mfma_f32_16x16x32_bf16(aq[ks], b0, sc[0], 0, 0, 0);
        sc[1] = __builtin_amdgcn_mfma_f32_16x16x32_bf16(aq[ks], b1, sc[1], 0, 0, 0);
      }
      // mask + scale + online softmax (row r at lane-group lg, reg r)
      float p0[4], p1[4];
      #pragma unroll
      for (int r=0;r<4;r++){
        int rowg = qt*64 + w*16 + lg*4 + r;
        int c0 = kt*32 + l15, c1 = c0 + 16;
        float v0 = sc[0][r]*SC, v1 = sc[1][r]*SC;
        if (c0 > rowg) v0 = -1e30f;
        if (c1 > rowg) v1 = -1e30f;
        float pm = fmaxf(v0, v1);
        pm = fmaxf(pm, __shfl_xor(pm, 1));
        pm = fmaxf(pm, __shfl_xor(pm, 2));
        pm = fmaxf(pm, __shfl_xor(pm, 4));
        pm = fmaxf(pm, __shfl_xor(pm, 8));
        float mn = fmaxf(mrow[r], pm);
        float f  = __expf(mrow[r] - mn);
        mrow[r] = mn;
        float e0 = __expf(v0 - mn), e1 = __expf(v1 - mn);
        float ps = e0 + e1;
        ps += __shfl_xor(ps, 1); ps += __shfl_xor(ps, 2);
        ps += __shfl_xor(ps, 4); ps += __shfl_xor(ps, 8);
        lrow[r] = lrow[r]*f + ps;
        p0[r] = e0; p1[r] = e1;
        #pragma unroll
        for (int df=0;df<8;df++) o[df][r] *= f;
      }
      // P -> LDS (per-wave region; no cross-wave sync needed)
      #pragma unroll
      for (int r=0;r<4;r++){
        Ps[w][(lg*4+r)*40 + l15]      = f2bf(p0[r]);
        Ps[w][(lg*4+r)*40 + 16 + l15] = f2bf(p1[r]);
      }
      // O += P V
      frag_ab pa = *(const frag_ab*)&Ps[w][l15*40 + lg*8];
      #pragma unroll
      for (int df=0;df<8;df++){
        frag_ab vb = *(const frag_ab*)&Vs[(df*16+l15)*40 + lg*8];
        o[df] = __builtin_amdgcn_mfma_f32_16x16x32_bf16(pa, vb, o[df], 0, 0, 0);
      }
    }
    // epilogue: O / l -> Attn[row][h*128+d]
    #pragma unroll
    for (int df=0;df<8;df++)
      #pragma unroll
      for (int r=0;r<4;r++){
        size_t row = qt*64 + w*16 + lg*4 + r;
        size_t col = (size_t)h*HD + df*16 + l15;
        Attn[row*HIDDEN + col] = f2bf(o[df][r] / lrow[r]);
      }
  }
}

// ---------------- launch ----------------
extern "C" void kernel_launch(void* const* d_in, const int* in_sizes, int n_in,
                              void* d_out, int out_size, void* d_ws, size_t ws_size,
                              hipStream_t stream) {
  const float* H  = (const float*)d_in[0];
  const int*  pos = (const int*)  d_in[1];
  const float* Wq = (const float*)d_in[2];
  const float* Wk = (const float*)d_in[3];
  const float* Wv = (const float*)d_in[4];
  const float* Wo = (const float*)d_in[5];
  float* out = (float*)d_out;

  char* ws = (char*)d_ws;
  // ws layout (total ~142.6 MB)
  short* WT   = (short*)(ws);                       // [6144][4096] bf16 (Wq^T | Wk^T | Wv^T)
  short* WoT  = (short*)(ws + 50331648);            // [4096][4096] bf16
  short* Hb   = (short*)(ws + 83886080);            // [2048][4096] bf16 (dead after QKV GEMM)
  short* QKV  = (short*)(ws + 100663296);           // [2048][6144] bf16
  short* Attn = (short*)(ws + 125829120);           // [2048][4096] bf16
  short* VT   = Hb;                                 // [1024][2048] bf16 (reuses Hb slot, 4 MB)

  k_cvt<<<8192, 256, 0, stream>>>(H, Hb, 2097152);
  k_transpose<<<dim3(128,128), 256, 0, stream>>>(Wq, WT,                        4096, 4096);
  k_transpose<<<dim3( 32,128), 256, 0, stream>>>(Wk, WT + (size_t)4096*4096,    4096, 1024);
  k_transpose<<<dim3( 32,128), 256, 0, stream>>>(Wv, WT + (size_t)5120*4096,    4096, 1024);
  k_transpose<<<dim3(128,128), 256, 0, stream>>>(Wo, WoT,                       4096, 4096);

  // QKV GEMM: M=2048 (8 tiles), N=6144 (48 tiles) -> 384 blocks (%8==0)
  k_gemm256<short><<<384, 512, 0, stream>>>(Hb, WT, QKV, 2048, 6144, 4096, 8);
  k_rope<<<20480, 256, 0, stream>>>(QKV, pos);
  k_transpose_v<<<dim3(64,32), 256, 0, stream>>>(QKV, VT);
  k_attn<<<dim3(16,32), 256, 0, stream>>>(QKV, VT, Attn);
  // Out-proj: M=2048 (8 tiles), N=4096 (32 tiles) -> 256 blocks (%8==0)
  k_gemm256<float><<<256, 512, 0, stream>>>(Attn, WoT, out, 2048, 4096, 4096, 8);
}

// Round 5
// 571.604 us; speedup vs baseline: 1.6404x; 1.0414x over previous
//
#include <hip/hip_runtime.h>
#include <hip/hip_bf16.h>
#include <math.h>

#define HIDDEN 4096
#define NH 32
#define NKV 8
#define HD 128
#define QKVC 6144   // 4096 (Q) + 1024 (K) + 1024 (V)

using f32x4  = __attribute__((ext_vector_type(4))) float;
using frag_ab = __attribute__((ext_vector_type(8))) short;

__device__ __forceinline__ short f2bf(float x){
  __hip_bfloat16 h = __float2bfloat16(x);
  return *reinterpret_cast<short*>(&h);
}
__device__ __forceinline__ float bf2f(short s){
  __hip_bfloat16 h = *reinterpret_cast<__hip_bfloat16*>(&s);
  return __bfloat162float(h);
}

__device__ __forceinline__ void load_lds16(const void* g, void* l){
  __builtin_amdgcn_global_load_lds(
      (const __attribute__((address_space(1))) unsigned*)g,
      (__attribute__((address_space(3))) unsigned*)l, 16, 0, 0);
}

__device__ __forceinline__ void hard_barrier(){
  asm volatile("" ::: "memory");
  __builtin_amdgcn_s_barrier();
  asm volatile("" ::: "memory");
}

// ---------------- fp32 -> bf16 convert (vectorized) ----------------
__global__ __launch_bounds__(256) void k_cvt(const float* __restrict__ X, short* __restrict__ Y, int n4){
  int i = blockIdx.x*256 + threadIdx.x;
  if (i >= n4) return;
  float4 v = reinterpret_cast<const float4*>(X)[i];
  short4 o;
  o.x = f2bf(v.x); o.y = f2bf(v.y); o.z = f2bf(v.z); o.w = f2bf(v.w);
  reinterpret_cast<short4*>(Y)[i] = o;
}

// ------------- W (K x N, fp32) -> WT (N x K, bf16) transpose -------------
__global__ __launch_bounds__(256) void k_transpose(const float* __restrict__ W, short* __restrict__ WT,
                                                   int K, int N){
  __shared__ float tile[32][33];
  int n0 = blockIdx.x*32, k0 = blockIdx.y*32;
  int tx = threadIdx.x & 31, ty = threadIdx.x >> 5;  // 32 x 8
  #pragma unroll
  for (int i=0;i<4;i++) tile[ty+i*8][tx] = W[(size_t)(k0+ty+i*8)*N + n0+tx];
  __syncthreads();
  #pragma unroll
  for (int i=0;i<4;i++) WT[(size_t)(n0+ty+i*8)*K + k0+tx] = f2bf(tile[tx][ty+i*8]);
}

// ------------- V block of QKV -> VT [1024 dg][2048 s] bf16 -------------
__global__ __launch_bounds__(256) void k_transpose_v(const short* __restrict__ QKV, short* __restrict__ VT){
  __shared__ short tile[32][40];
  int s0 = blockIdx.x*32, d0 = blockIdx.y*32;   // grid (64, 32)
  int tx = threadIdx.x & 31, ty = threadIdx.x >> 5;
  #pragma unroll
  for (int i=0;i<4;i++) tile[ty+i*8][tx] = QKV[(size_t)(s0+ty+i*8)*QKVC + 5120 + d0+tx];
  __syncthreads();
  #pragma unroll
  for (int i=0;i<4;i++) VT[(size_t)(d0+ty+i*8)*2048 + s0+tx] = tile[tx][ty+i*8];
}

// ------------- pipelined bf16 GEMM: C[M][N] = A[M][K] * BT[N][K]^T -------------
// BM=256, BN=128, BK=32; 512 threads = 8 waves (4M x 2N); per-wave 64x64 output.
// 4-buffer LDS ring (96 KB); counted vmcnt (T3+T4); raw s_barrier; setprio (T5);
// bijective XCD swizzle (T1); T2 chunk-XOR swizzle: LDS slot (row, c) holds global
// chunk c ^ ((row>>1)&3) -- applied on the GLOBAL source (m173), LDS dest linear.
template<typename OutT>
__global__ __launch_bounds__(512, 2) void k_gemm256(const short* __restrict__ A, const short* __restrict__ BT,
                                                    OutT* __restrict__ C, int M, int N, int K, int mt){
  __shared__ __align__(16) short L[49152];   // 4 buffers x (A 8192 + B 4096) shorts
  // XCD-aware block swizzle (gridDim.x % 8 == 0)
  const int nwg = gridDim.x, cpx = nwg >> 3;
  const int bid = blockIdx.x;
  const int swz = (bid & 7) * cpx + (bid >> 3);
  const int bx = swz % mt, by = swz / mt;
  const int brow = bx*256, bcol = by*128;
  const int tid = threadIdx.x, lane = tid & 63, wid = tid >> 6;
  const int wr = wid >> 1, wc = wid & 1;
  const int l15 = lane & 15, lg = lane >> 4;
  const int nk = K >> 5;

  // staging: LDS slot s holds (row = s>>2, chunk = s&3); source chunk pre-swizzled
  const int sr0 = tid >> 2;                                   // A row 0..127 (+128), B row 0..127
  const int scw = ((tid & 3) ^ ((tid >> 3) & 3)) << 3;        // swizzled source chunk (shorts)
  const short* Aponly = A + (size_t)brow*K;
  const short* Bponly = BT + (size_t)bcol*K;

  f32x4 acc[4][4] = {};

  #define STAGE(kt) do { \
    int _b = (kt) & 3; \
    load_lds16(Aponly + (size_t)sr0*K       + (kt)*32 + scw, &L[_b*12288 + tid*8]); \
    load_lds16(Aponly + (size_t)(sr0+128)*K + (kt)*32 + scw, &L[_b*12288 + (tid+512)*8]); \
    load_lds16(Bponly + (size_t)sr0*K       + (kt)*32 + scw, &L[_b*12288 + 8192 + tid*8]); \
  } while(0)

  // prologue: stage tiles 0,1,2 (9 loads/thread), drain to tile0 landed
  STAGE(0); STAGE(1); STAGE(2);
  asm volatile("s_waitcnt vmcnt(6)" ::: "memory");
  hard_barrier();

  // reader-side swizzled chunk: row base (wr*64+m*16) is 0 mod 32 -> swizzle = f(l15) only
  const int rchunk = ((lg ^ ((l15 >> 1) & 3)) << 3);

  for (int t = 0; t < nk; ++t){
    const int b = t & 3;
    const short* Ab = &L[b*12288];
    const short* Bb = &L[b*12288 + 8192];
    frag_ab af[4], bf[4];
    #pragma unroll
    for (int m=0;m<4;m++) af[m] = *(const frag_ab*)&Ab[(wr*64 + m*16 + l15)*32 + rchunk];
    #pragma unroll
    for (int n=0;n<4;n++) bf[n] = *(const frag_ab*)&Bb[(wc*64 + n*16 + l15)*32 + rchunk];
    if (t + 3 < nk) STAGE(t+3);
    hard_barrier();
    __builtin_amdgcn_s_setprio(1);
    #pragma unroll
    for (int m=0;m<4;m++)
      #pragma unroll
      for (int n=0;n<4;n++)
        acc[m][n] = __builtin_amdgcn_mfma_f32_16x16x32_bf16(af[m], bf[n], acc[m][n], 0, 0, 0);
    __builtin_amdgcn_s_setprio(0);
    // boundary: guarantee tile t+1 fully landed; keep t+2,t+3 in flight
    if (t < nk-3)       asm volatile("s_waitcnt vmcnt(6)" ::: "memory");
    else if (t == nk-3) asm volatile("s_waitcnt vmcnt(3)" ::: "memory");
    else                asm volatile("s_waitcnt vmcnt(0)" ::: "memory");
    hard_barrier();
  }
  #undef STAGE

  // epilogue
  #pragma unroll
  for (int m=0;m<4;m++)
    #pragma unroll
    for (int n=0;n<4;n++)
      #pragma unroll
      for (int r=0;r<4;r++){
        size_t row = brow + wr*64 + m*16 + lg*4 + r;
        size_t col = bcol + wc*64 + n*16 + l15;
        float v = acc[m][n][r];
        if constexpr (sizeof(OutT) == 4) C[row*(size_t)N + col] = v;
        else                             C[row*(size_t)N + col] = f2bf(v);
      }
}

// ---------------- RoPE in-place on QKV (Q heads + K heads) ----------------
__global__ __launch_bounds__(256) void k_rope(short* __restrict__ QKV, const int* __restrict__ pos){
  int idx = blockIdx.x*256 + threadIdx.x;     // total = 2048 * 40 * 64
  int j   = idx & 63;
  int hh  = (idx >> 6) % 40;
  int row = (idx >> 6) / 40;
  int colbase = hh < NH ? hh*HD : HIDDEN + (hh-NH)*HD;
  size_t base = (size_t)row*QKVC + colbase;
  float x1 = bf2f(QKV[base + j]), x2 = bf2f(QKV[base + j + 64]);
  float ang = (float)pos[row] * exp2f(-(float)j * 0.2076205059304601f); // log2(1e4)/64
  float sn, cs; sincosf(ang, &sn, &cs);
  QKV[base + j]      = f2bf(x1*cs - x2*sn);
  QKV[base + j + 64] = f2bf(x2*cs + x1*sn);
}

// ---------------- flash attention ----------------
// block = (pair of q-tiles {qt, 31-qt}, 1 head) -> uniform 66 kv-tiles per block
__global__ __launch_bounds__(256) void k_attn(const short* __restrict__ QKV, const short* __restrict__ VT,
                                              short* __restrict__ Attn){
  const int pairI = blockIdx.x, h = blockIdx.y, kvh = h >> 2;
  const int t = threadIdx.x, lane = t & 63, w = t >> 6;
  const int l15 = lane & 15, lg = lane >> 4;
  __shared__ __align__(16) short Ks[32*128];      // K tile, XOR-swizzled (write via pre-swizzled src)
  __shared__ __align__(16) short Vs[128*40];      // V^T tile [d][k], padded stride 40
  __shared__ __align__(16) short Ps[4][16*40];    // per-wave P tile, stride 40

  const float SC = 0.08838834764831845f;  // 1/sqrt(128)

  for (int half = 0; half < 2; ++half){
    const int qt = half ? (31 - pairI) : pairI;
    // Q fragments (16 rows per wave) from global, held in registers
    frag_ab aq[4];
    {
      const short* qrow = QKV + (size_t)(qt*64 + w*16 + l15)*QKVC + h*HD;
      #pragma unroll
      for (int ks=0;ks<4;ks++) aq[ks] = *(const frag_ab*)&qrow[ks*32 + lg*8];
    }
    float mrow[4], lrow[4];
    #pragma unroll
    for (int r=0;r<4;r++){ mrow[r] = -INFINITY; lrow[r] = 0.f; }
    f32x4 o[8] = {};
    const int nkv = 2*qt + 2;
    for (int kt = 0; kt < nkv; ++kt){
      __syncthreads();
      // stage K via global_load_lds, source pre-swizzled so LDS holds row*128 + (c ^ ((row&7)<<3))
      #pragma unroll
      for (int i=0;i<2;i++){
        int s = t + i*256;             // 512 chunks of 16B
        int row = s >> 4;              // 0..31
        int c8  = (s & 15) << 3;       // 0..120
        int csw = c8 ^ ((row & 7) << 3);
        load_lds16(QKV + (size_t)(kt*32 + row)*QKVC + HIDDEN + kvh*HD + csw, &Ks[s*8]);
      }
      // stage V^T tile from pre-transposed global VT (vectorized, padded stride)
      #pragma unroll
      for (int i=0;i<2;i++){
        int s = t + i*256;             // 512 chunks of 8 shorts
        int d  = s >> 2;               // 0..127
        int k8 = (s & 3) << 3;         // 0,8,16,24
        uint4 vv = *(const uint4*)&VT[(size_t)(kvh*HD + d)*2048 + kt*32 + k8];
        *(uint4*)&Vs[d*40 + k8] = vv;
      }
      __syncthreads();
      // S = Q K^T  (two 16-col fragments)
      f32x4 sc[2] = {};
      #pragma unroll
      for (int ks=0;ks<4;ks++){
        int c = ks*32 + lg*8;
        frag_ab b0 = *(const frag_ab*)&Ks[l15*128      + (c ^ ((l15 & 7) << 3))];
        frag_ab b1 = *(const frag_ab*)&Ks[(16+l15)*128 + (c ^ ((l15 & 7) << 3))];
        sc[0] = __builtin_amdgcn_mfma_f32_16x16x32_bf16(aq[ks], b0, sc[0], 0, 0, 0);
        sc[1] = __builtin_amdgcn_mfma_f32_16x16x32_bf16(aq[ks], b1, sc[1], 0, 0, 0);
      }
      // mask + scale + online softmax (row r at lane-group lg, reg r)
      float p0[4], p1[4];
      #pragma unroll
      for (int r=0;r<4;r++){
        int rowg = qt*64 + w*16 + lg*4 + r;
        int c0 = kt*32 + l15, c1 = c0 + 16;
        float v0 = sc[0][r]*SC, v1 = sc[1][r]*SC;
        if (c0 > rowg) v0 = -1e30f;
        if (c1 > rowg) v1 = -1e30f;
        float pm = fmaxf(v0, v1);
        pm = fmaxf(pm, __shfl_xor(pm, 1));
        pm = fmaxf(pm, __shfl_xor(pm, 2));
        pm = fmaxf(pm, __shfl_xor(pm, 4));
        pm = fmaxf(pm, __shfl_xor(pm, 8));
        float mn = fmaxf(mrow[r], pm);
        float f  = __expf(mrow[r] - mn);
        mrow[r] = mn;
        float e0 = __expf(v0 - mn), e1 = __expf(v1 - mn);
        float ps = e0 + e1;
        ps += __shfl_xor(ps, 1); ps += __shfl_xor(ps, 2);
        ps += __shfl_xor(ps, 4); ps += __shfl_xor(ps, 8);
        lrow[r] = lrow[r]*f + ps;
        p0[r] = e0; p1[r] = e1;
        #pragma unroll
        for (int df=0;df<8;df++) o[df][r] *= f;
      }
      // P -> LDS (per-wave region; no cross-wave sync needed)
      #pragma unroll
      for (int r=0;r<4;r++){
        Ps[w][(lg*4+r)*40 + l15]      = f2bf(p0[r]);
        Ps[w][(lg*4+r)*40 + 16 + l15] = f2bf(p1[r]);
      }
      // O += P V
      frag_ab pa = *(const frag_ab*)&Ps[w][l15*40 + lg*8];
      #pragma unroll
      for (int df=0;df<8;df++){
        frag_ab vb = *(const frag_ab*)&Vs[(df*16+l15)*40 + lg*8];
        o[df] = __builtin_amdgcn_mfma_f32_16x16x32_bf16(pa, vb, o[df], 0, 0, 0);
      }
    }
    // epilogue: O / l -> Attn[row][h*128+d]
    #pragma unroll
    for (int df=0;df<8;df++)
      #pragma unroll
      for (int r=0;r<4;r++){
        size_t row = qt*64 + w*16 + lg*4 + r;
        size_t col = (size_t)h*HD + df*16 + l15;
        Attn[row*HIDDEN + col] = f2bf(o[df][r] / lrow[r]);
      }
  }
}

// ---------------- launch ----------------
extern "C" void kernel_launch(void* const* d_in, const int* in_sizes, int n_in,
                              void* d_out, int out_size, void* d_ws, size_t ws_size,
                              hipStream_t stream) {
  const float* H  = (const float*)d_in[0];
  const int*  pos = (const int*)  d_in[1];
  const float* Wq = (const float*)d_in[2];
  const float* Wk = (const float*)d_in[3];
  const float* Wv = (const float*)d_in[4];
  const float* Wo = (const float*)d_in[5];
  float* out = (float*)d_out;

  char* ws = (char*)d_ws;
  // ws layout (total ~142.6 MB)
  short* WT   = (short*)(ws);                       // [6144][4096] bf16 (Wq^T | Wk^T | Wv^T)
  short* WoT  = (short*)(ws + 50331648);            // [4096][4096] bf16
  short* Hb   = (short*)(ws + 83886080);            // [2048][4096] bf16 (dead after QKV GEMM)
  short* QKV  = (short*)(ws + 100663296);           // [2048][6144] bf16
  short* Attn = (short*)(ws + 125829120);           // [2048][4096] bf16
  short* VT   = Hb;                                 // [1024][2048] bf16 (reuses Hb slot, 4 MB)

  k_cvt<<<8192, 256, 0, stream>>>(H, Hb, 2097152);
  k_transpose<<<dim3(128,128), 256, 0, stream>>>(Wq, WT,                        4096, 4096);
  k_transpose<<<dim3( 32,128), 256, 0, stream>>>(Wk, WT + (size_t)4096*4096,    4096, 1024);
  k_transpose<<<dim3( 32,128), 256, 0, stream>>>(Wv, WT + (size_t)5120*4096,    4096, 1024);
  k_transpose<<<dim3(128,128), 256, 0, stream>>>(Wo, WoT,                       4096, 4096);

  // QKV GEMM: M=2048 (8 tiles), N=6144 (48 tiles) -> 384 blocks (%8==0)
  k_gemm256<short><<<384, 512, 0, stream>>>(Hb, WT, QKV, 2048, 6144, 4096, 8);
  k_rope<<<20480, 256, 0, stream>>>(QKV, pos);
  k_transpose_v<<<dim3(64,32), 256, 0, stream>>>(QKV, VT);
  k_attn<<<dim3(16,32), 256, 0, stream>>>(QKV, VT, Attn);
  // Out-proj: M=2048 (8 tiles), N=4096 (32 tiles) -> 256 blocks (%8==0)
  k_gemm256<float><<<256, 512, 0, stream>>>(Attn, WoT, out, 2048, 4096, 4096, 8);
}

// Round 6
// 560.214 us; speedup vs baseline: 1.6738x; 1.0203x over previous
//
#include <hip/hip_runtime.h>
#include <hip/hip_bf16.h>
#include <math.h>

#define HIDDEN 4096
#define NH 32
#define NKV 8
#define HD 128
#define QKVC 6144   // 4096 (Q) + 1024 (K) + 1024 (V)

using f32x4  = __attribute__((ext_vector_type(4))) float;
using frag_ab = __attribute__((ext_vector_type(8))) short;

__device__ __forceinline__ short f2bf(float x){
  __hip_bfloat16 h = __float2bfloat16(x);
  return *reinterpret_cast<short*>(&h);
}
__device__ __forceinline__ float bf2f(short s){
  __hip_bfloat16 h = *reinterpret_cast<__hip_bfloat16*>(&s);
  return __bfloat162float(h);
}

__device__ __forceinline__ void load_lds16(const void* g, void* l){
  __builtin_amdgcn_global_load_lds(
      (const __attribute__((address_space(1))) unsigned*)g,
      (__attribute__((address_space(3))) unsigned*)l, 16, 0, 0);
}

__device__ __forceinline__ void hard_barrier(){
  asm volatile("" ::: "memory");
  __builtin_amdgcn_s_barrier();
  asm volatile("" ::: "memory");
}

// ---------------- fp32 -> bf16 convert (vectorized) ----------------
__global__ __launch_bounds__(256) void k_cvt(const float* __restrict__ X, short* __restrict__ Y, int n4){
  int i = blockIdx.x*256 + threadIdx.x;
  if (i >= n4) return;
  float4 v = reinterpret_cast<const float4*>(X)[i];
  short4 o;
  o.x = f2bf(v.x); o.y = f2bf(v.y); o.z = f2bf(v.z); o.w = f2bf(v.w);
  reinterpret_cast<short4*>(Y)[i] = o;
}

// ------------- W (K x N, fp32) -> WT (N x K, bf16) transpose -------------
__global__ __launch_bounds__(256) void k_transpose(const float* __restrict__ W, short* __restrict__ WT,
                                                   int K, int N){
  __shared__ float tile[32][33];
  int n0 = blockIdx.x*32, k0 = blockIdx.y*32;
  int tx = threadIdx.x & 31, ty = threadIdx.x >> 5;  // 32 x 8
  #pragma unroll
  for (int i=0;i<4;i++) tile[ty+i*8][tx] = W[(size_t)(k0+ty+i*8)*N + n0+tx];
  __syncthreads();
  #pragma unroll
  for (int i=0;i<4;i++) WT[(size_t)(n0+ty+i*8)*K + k0+tx] = f2bf(tile[tx][ty+i*8]);
}

// ------------- V block of QKV -> VT [1024 dg][2048 s] bf16 -------------
__global__ __launch_bounds__(256) void k_transpose_v(const short* __restrict__ QKV, short* __restrict__ VT){
  __shared__ short tile[32][40];
  int s0 = blockIdx.x*32, d0 = blockIdx.y*32;   // grid (64, 32)
  int tx = threadIdx.x & 31, ty = threadIdx.x >> 5;
  #pragma unroll
  for (int i=0;i<4;i++) tile[ty+i*8][tx] = QKV[(size_t)(s0+ty+i*8)*QKVC + 5120 + d0+tx];
  __syncthreads();
  #pragma unroll
  for (int i=0;i<4;i++) VT[(size_t)(d0+ty+i*8)*2048 + s0+tx] = tile[tx][ty+i*8];
}

// ------------- pipelined bf16 GEMM: C[M][N] = A[M][K] * BT[N][K]^T -------------
// BM=256, BN=128, BK=32; 512 threads = 8 waves (4M x 2N); per-wave 64x64 output.
// 3-buffer LDS ring (72 KB -> 2 blocks/CU for cross-block overlap, m114);
// ONE barrier per K-step; counted vmcnt(3); setprio (T5); XCD swizzle (T1);
// T2 chunk-XOR swizzle applied on the GLOBAL source (m173), LDS dest linear.
template<typename OutT>
__global__ __launch_bounds__(512, 4) void k_gemm256(const short* __restrict__ A, const short* __restrict__ BT,
                                                    OutT* __restrict__ C, int M, int N, int K, int mt){
  __shared__ __align__(16) short L[36864];   // 3 buffers x (A 8192 + B 4096) shorts = 72 KB
  // XCD-aware block swizzle (gridDim.x % 8 == 0)
  const int nwg = gridDim.x, cpx = nwg >> 3;
  const int bid = blockIdx.x;
  const int swz = (bid & 7) * cpx + (bid >> 3);
  const int bx = swz % mt, by = swz / mt;
  const int brow = bx*256, bcol = by*128;
  const int tid = threadIdx.x, lane = tid & 63, wid = tid >> 6;
  const int wr = wid >> 1, wc = wid & 1;
  const int l15 = lane & 15, lg = lane >> 4;
  const int nk = K >> 5;

  // staging: LDS slot s holds (row = s>>2, chunk = s&3); source chunk pre-swizzled
  const int sr0 = tid >> 2;                                   // A row 0..127 (+128), B row 0..127
  const int scw = ((tid & 3) ^ ((tid >> 3) & 3)) << 3;        // swizzled source chunk (shorts)
  const short* Aponly = A + (size_t)brow*K;
  const short* Bponly = BT + (size_t)bcol*K;

  f32x4 acc[4][4] = {};

  #define STAGE(kt, bb) do { \
    load_lds16(Aponly + (size_t)sr0*K       + (kt)*32 + scw, &L[(bb)*12288 + tid*8]); \
    load_lds16(Aponly + (size_t)(sr0+128)*K + (kt)*32 + scw, &L[(bb)*12288 + (tid+512)*8]); \
    load_lds16(Bponly + (size_t)sr0*K       + (kt)*32 + scw, &L[(bb)*12288 + 8192 + tid*8]); \
  } while(0)

  // prologue: stage tiles 0,1; wait tile0 landed (3 of 6 outstanding)
  STAGE(0, 0); STAGE(1, 1);
  asm volatile("s_waitcnt vmcnt(3)" ::: "memory");
  hard_barrier();

  // reader-side swizzled chunk: row base (wr*64+m*16) is 0 mod 32 -> swizzle = f(l15) only
  const int rchunk = ((lg ^ ((l15 >> 1) & 3)) << 3);

  int bt = 0;                        // buffer holding tile t
  for (int t = 0; t < nk; ++t){
    const short* Ab = &L[bt*12288];
    const short* Bb = &L[bt*12288 + 8192];
    frag_ab af[4], bf[4];
    #pragma unroll
    for (int m=0;m<4;m++) af[m] = *(const frag_ab*)&Ab[(wr*64 + m*16 + l15)*32 + rchunk];
    #pragma unroll
    for (int n=0;n<4;n++) bf[n] = *(const frag_ab*)&Bb[(wc*64 + n*16 + l15)*32 + rchunk];
    if (t + 2 < nk){
      int bs = bt + 2; if (bs >= 3) bs -= 3;   // (t+2) % 3
      STAGE(t+2, bs);
    }
    __builtin_amdgcn_s_setprio(1);
    #pragma unroll
    for (int m=0;m<4;m++)
      #pragma unroll
      for (int n=0;n<4;n++)
        acc[m][n] = __builtin_amdgcn_mfma_f32_16x16x32_bf16(af[m], bf[n], acc[m][n], 0, 0, 0);
    __builtin_amdgcn_s_setprio(0);
    // boundary: guarantee tile t+1 fully landed; keep t+2 in flight
    if (t < nk-2) asm volatile("s_waitcnt vmcnt(3)" ::: "memory");
    else          asm volatile("s_waitcnt vmcnt(0)" ::: "memory");
    hard_barrier();
    bt = (bt == 2) ? 0 : bt + 1;
  }
  #undef STAGE

  // epilogue
  #pragma unroll
  for (int m=0;m<4;m++)
    #pragma unroll
    for (int n=0;n<4;n++)
      #pragma unroll
      for (int r=0;r<4;r++){
        size_t row = brow + wr*64 + m*16 + lg*4 + r;
        size_t col = bcol + wc*64 + n*16 + l15;
        float v = acc[m][n][r];
        if constexpr (sizeof(OutT) == 4) C[row*(size_t)N + col] = v;
        else                             C[row*(size_t)N + col] = f2bf(v);
      }
}

// ---------------- RoPE in-place on QKV (Q heads + K heads) ----------------
__global__ __launch_bounds__(256) void k_rope(short* __restrict__ QKV, const int* __restrict__ pos){
  int idx = blockIdx.x*256 + threadIdx.x;     // total = 2048 * 40 * 64
  int j   = idx & 63;
  int hh  = (idx >> 6) % 40;
  int row = (idx >> 6) / 40;
  int colbase = hh < NH ? hh*HD : HIDDEN + (hh-NH)*HD;
  size_t base = (size_t)row*QKVC + colbase;
  float x1 = bf2f(QKV[base + j]), x2 = bf2f(QKV[base + j + 64]);
  float ang = (float)pos[row] * exp2f(-(float)j * 0.2076205059304601f); // log2(1e4)/64
  float sn, cs; sincosf(ang, &sn, &cs);
  QKV[base + j]      = f2bf(x1*cs - x2*sn);
  QKV[base + j + 64] = f2bf(x2*cs + x1*sn);
}

// ---------------- flash attention ----------------
// block = (pair of q-tiles {qt, 31-qt}, 1 head) -> uniform 66 kv-tiles per block
__global__ __launch_bounds__(256) void k_attn(const short* __restrict__ QKV, const short* __restrict__ VT,
                                              short* __restrict__ Attn){
  const int pairI = blockIdx.x, h = blockIdx.y, kvh = h >> 2;
  const int t = threadIdx.x, lane = t & 63, w = t >> 6;
  const int l15 = lane & 15, lg = lane >> 4;
  __shared__ __align__(16) short Ks[32*128];      // K tile, XOR-swizzled (write via pre-swizzled src)
  __shared__ __align__(16) short Vs[128*40];      // V^T tile [d][k], padded stride 40
  __shared__ __align__(16) short Ps[4][16*40];    // per-wave P tile, stride 40

  const float SC = 0.08838834764831845f;  // 1/sqrt(128)

  for (int half = 0; half < 2; ++half){
    const int qt = half ? (31 - pairI) : pairI;
    // Q fragments (16 rows per wave) from global, held in registers
    frag_ab aq[4];
    {
      const short* qrow = QKV + (size_t)(qt*64 + w*16 + l15)*QKVC + h*HD;
      #pragma unroll
      for (int ks=0;ks<4;ks++) aq[ks] = *(const frag_ab*)&qrow[ks*32 + lg*8];
    }
    float mrow[4], lrow[4];
    #pragma unroll
    for (int r=0;r<4;r++){ mrow[r] = -INFINITY; lrow[r] = 0.f; }
    f32x4 o[8] = {};
    const int nkv = 2*qt + 2;
    for (int kt = 0; kt < nkv; ++kt){
      __syncthreads();
      // stage K via global_load_lds, source pre-swizzled so LDS holds row*128 + (c ^ ((row&7)<<3))
      #pragma unroll
      for (int i=0;i<2;i++){
        int s = t + i*256;             // 512 chunks of 16B
        int row = s >> 4;              // 0..31
        int c8  = (s & 15) << 3;       // 0..120
        int csw = c8 ^ ((row & 7) << 3);
        load_lds16(QKV + (size_t)(kt*32 + row)*QKVC + HIDDEN + kvh*HD + csw, &Ks[s*8]);
      }
      // stage V^T tile from pre-transposed global VT (vectorized, padded stride)
      #pragma unroll
      for (int i=0;i<2;i++){
        int s = t + i*256;             // 512 chunks of 8 shorts
        int d  = s >> 2;               // 0..127
        int k8 = (s & 3) << 3;         // 0,8,16,24
        uint4 vv = *(const uint4*)&VT[(size_t)(kvh*HD + d)*2048 + kt*32 + k8];
        *(uint4*)&Vs[d*40 + k8] = vv;
      }
      __syncthreads();
      // S = Q K^T  (two 16-col fragments)
      f32x4 sc[2] = {};
      #pragma unroll
      for (int ks=0;ks<4;ks++){
        int c = ks*32 + lg*8;
        frag_ab b0 = *(const frag_ab*)&Ks[l15*128      + (c ^ ((l15 & 7) << 3))];
        frag_ab b1 = *(const frag_ab*)&Ks[(16+l15)*128 + (c ^ ((l15 & 7) << 3))];
        sc[0] = __builtin_amdgcn_mfma_f32_16x16x32_bf16(aq[ks], b0, sc[0], 0, 0, 0);
        sc[1] = __builtin_amdgcn_mfma_f32_16x16x32_bf16(aq[ks], b1, sc[1], 0, 0, 0);
      }
      // mask + scale + online softmax (row r at lane-group lg, reg r)
      float p0[4], p1[4];
      #pragma unroll
      for (int r=0;r<4;r++){
        int rowg = qt*64 + w*16 + lg*4 + r;
        int c0 = kt*32 + l15, c1 = c0 + 16;
        float v0 = sc[0][r]*SC, v1 = sc[1][r]*SC;
        if (c0 > rowg) v0 = -1e30f;
        if (c1 > rowg) v1 = -1e30f;
        float pm = fmaxf(v0, v1);
        pm = fmaxf(pm, __shfl_xor(pm, 1));
        pm = fmaxf(pm, __shfl_xor(pm, 2));
        pm = fmaxf(pm, __shfl_xor(pm, 4));
        pm = fmaxf(pm, __shfl_xor(pm, 8));
        float mn = fmaxf(mrow[r], pm);
        float f  = __expf(mrow[r] - mn);
        mrow[r] = mn;
        float e0 = __expf(v0 - mn), e1 = __expf(v1 - mn);
        float ps = e0 + e1;
        ps += __shfl_xor(ps, 1); ps += __shfl_xor(ps, 2);
        ps += __shfl_xor(ps, 4); ps += __shfl_xor(ps, 8);
        lrow[r] = lrow[r]*f + ps;
        p0[r] = e0; p1[r] = e1;
        #pragma unroll
        for (int df=0;df<8;df++) o[df][r] *= f;
      }
      // P -> LDS (per-wave region; no cross-wave sync needed)
      #pragma unroll
      for (int r=0;r<4;r++){
        Ps[w][(lg*4+r)*40 + l15]      = f2bf(p0[r]);
        Ps[w][(lg*4+r)*40 + 16 + l15] = f2bf(p1[r]);
      }
      // O += P V
      frag_ab pa = *(const frag_ab*)&Ps[w][l15*40 + lg*8];
      #pragma unroll
      for (int df=0;df<8;df++){
        frag_ab vb = *(const frag_ab*)&Vs[(df*16+l15)*40 + lg*8];
        o[df] = __builtin_amdgcn_mfma_f32_16x16x32_bf16(pa, vb, o[df], 0, 0, 0);
      }
    }
    // epilogue: O / l -> Attn[row][h*128+d]
    #pragma unroll
    for (int df=0;df<8;df++)
      #pragma unroll
      for (int r=0;r<4;r++){
        size_t row = qt*64 + w*16 + lg*4 + r;
        size_t col = (size_t)h*HD + df*16 + l15;
        Attn[row*HIDDEN + col] = f2bf(o[df][r] / lrow[r]);
      }
  }
}

// ---------------- launch ----------------
extern "C" void kernel_launch(void* const* d_in, const int* in_sizes, int n_in,
                              void* d_out, int out_size, void* d_ws, size_t ws_size,
                              hipStream_t stream) {
  const float* H  = (const float*)d_in[0];
  const int*  pos = (const int*)  d_in[1];
  const float* Wq = (const float*)d_in[2];
  const float* Wk = (const float*)d_in[3];
  const float* Wv = (const float*)d_in[4];
  const float* Wo = (const float*)d_in[5];
  float* out = (float*)d_out;

  char* ws = (char*)d_ws;
  // ws layout (total ~142.6 MB)
  short* WT   = (short*)(ws);                       // [6144][4096] bf16 (Wq^T | Wk^T | Wv^T)
  short* WoT  = (short*)(ws + 50331648);            // [4096][4096] bf16
  short* Hb   = (short*)(ws + 83886080);            // [2048][4096] bf16 (dead after QKV GEMM)
  short* QKV  = (short*)(ws + 100663296);           // [2048][6144] bf16
  short* Attn = (short*)(ws + 125829120);           // [2048][4096] bf16
  short* VT   = Hb;                                 // [1024][2048] bf16 (reuses Hb slot, 4 MB)

  k_cvt<<<8192, 256, 0, stream>>>(H, Hb, 2097152);
  k_transpose<<<dim3(128,128), 256, 0, stream>>>(Wq, WT,                        4096, 4096);
  k_transpose<<<dim3( 32,128), 256, 0, stream>>>(Wk, WT + (size_t)4096*4096,    4096, 1024);
  k_transpose<<<dim3( 32,128), 256, 0, stream>>>(Wv, WT + (size_t)5120*4096,    4096, 1024);
  k_transpose<<<dim3(128,128), 256, 0, stream>>>(Wo, WoT,                       4096, 4096);

  // QKV GEMM: M=2048 (8 tiles), N=6144 (48 tiles) -> 384 blocks (%8==0)
  k_gemm256<short><<<384, 512, 0, stream>>>(Hb, WT, QKV, 2048, 6144, 4096, 8);
  k_rope<<<20480, 256, 0, stream>>>(QKV, pos);
  k_transpose_v<<<dim3(64,32), 256, 0, stream>>>(QKV, VT);
  k_attn<<<dim3(16,32), 256, 0, stream>>>(QKV, VT, Attn);
  // Out-proj: M=2048 (8 tiles), N=4096 (32 tiles) -> 256 blocks (%8==0)
  k_gemm256<float><<<256, 512, 0, stream>>>(Attn, WoT, out, 2048, 4096, 4096, 8);
}

// Round 7
// 510.953 us; speedup vs baseline: 1.8351x; 1.0964x over previous
//
#include <hip/hip_runtime.h>
#include <hip/hip_bf16.h>
#include <math.h>

#define HIDDEN 4096
#define NH 32
#define NKV 8
#define HD 128
#define QKVC 6144   // 4096 (Q) + 1024 (K) + 1024 (V)

using f32x4  = __attribute__((ext_vector_type(4))) float;
using frag_ab = __attribute__((ext_vector_type(8))) short;

__device__ __forceinline__ short f2bf(float x){
  __hip_bfloat16 h = __float2bfloat16(x);
  return *reinterpret_cast<short*>(&h);
}
__device__ __forceinline__ float bf2f(short s){
  __hip_bfloat16 h = *reinterpret_cast<__hip_bfloat16*>(&s);
  return __bfloat162float(h);
}

__device__ __forceinline__ void load_lds16(const void* g, void* l){
  __builtin_amdgcn_global_load_lds(
      (const __attribute__((address_space(1))) unsigned*)g,
      (__attribute__((address_space(3))) unsigned*)l, 16, 0, 0);
}

__device__ __forceinline__ void hard_barrier(){
  asm volatile("" ::: "memory");
  __builtin_amdgcn_s_barrier();
  asm volatile("" ::: "memory");
}

// ---------------- fp32 -> bf16 convert (vectorized) ----------------
__global__ __launch_bounds__(256) void k_cvt(const float* __restrict__ X, short* __restrict__ Y, int n4){
  int i = blockIdx.x*256 + threadIdx.x;
  if (i >= n4) return;
  float4 v = reinterpret_cast<const float4*>(X)[i];
  short4 o;
  o.x = f2bf(v.x); o.y = f2bf(v.y); o.z = f2bf(v.z); o.w = f2bf(v.w);
  reinterpret_cast<short4*>(Y)[i] = o;
}

// ------------- W (K x N, fp32) -> WT (N x K, bf16) transpose -------------
__global__ __launch_bounds__(256) void k_transpose(const float* __restrict__ W, short* __restrict__ WT,
                                                   int K, int N){
  __shared__ float tile[32][33];
  int n0 = blockIdx.x*32, k0 = blockIdx.y*32;
  int tx = threadIdx.x & 31, ty = threadIdx.x >> 5;  // 32 x 8
  #pragma unroll
  for (int i=0;i<4;i++) tile[ty+i*8][tx] = W[(size_t)(k0+ty+i*8)*N + n0+tx];
  __syncthreads();
  #pragma unroll
  for (int i=0;i<4;i++) WT[(size_t)(n0+ty+i*8)*K + k0+tx] = f2bf(tile[tx][ty+i*8]);
}

// ------------- V block of QKV -> VT [1024 dg][2048 s] bf16 -------------
__global__ __launch_bounds__(256) void k_transpose_v(const short* __restrict__ QKV, short* __restrict__ VT){
  __shared__ short tile[32][40];
  int s0 = blockIdx.x*32, d0 = blockIdx.y*32;   // grid (64, 32)
  int tx = threadIdx.x & 31, ty = threadIdx.x >> 5;
  #pragma unroll
  for (int i=0;i<4;i++) tile[ty+i*8][tx] = QKV[(size_t)(s0+ty+i*8)*QKVC + 5120 + d0+tx];
  __syncthreads();
  #pragma unroll
  for (int i=0;i<4;i++) VT[(size_t)(d0+ty+i*8)*2048 + s0+tx] = tile[tx][ty+i*8];
}

// ------------- pipelined bf16 GEMM: C[M][N] = A[M][K] * BT[N][K]^T -------------
template<typename OutT>
__global__ __launch_bounds__(512, 4) void k_gemm256(const short* __restrict__ A, const short* __restrict__ BT,
                                                    OutT* __restrict__ C, int M, int N, int K, int mt){
  __shared__ __align__(16) short L[36864];   // 3 buffers x (A 8192 + B 4096) shorts = 72 KB
  const int nwg = gridDim.x, cpx = nwg >> 3;
  const int bid = blockIdx.x;
  const int swz = (bid & 7) * cpx + (bid >> 3);
  const int bx = swz % mt, by = swz / mt;
  const int brow = bx*256, bcol = by*128;
  const int tid = threadIdx.x, lane = tid & 63, wid = tid >> 6;
  const int wr = wid >> 1, wc = wid & 1;
  const int l15 = lane & 15, lg = lane >> 4;
  const int nk = K >> 5;

  const int sr0 = tid >> 2;
  const int scw = ((tid & 3) ^ ((tid >> 3) & 3)) << 3;
  const short* Aponly = A + (size_t)brow*K;
  const short* Bponly = BT + (size_t)bcol*K;

  f32x4 acc[4][4] = {};

  #define STAGE(kt, bb) do { \
    load_lds16(Aponly + (size_t)sr0*K       + (kt)*32 + scw, &L[(bb)*12288 + tid*8]); \
    load_lds16(Aponly + (size_t)(sr0+128)*K + (kt)*32 + scw, &L[(bb)*12288 + (tid+512)*8]); \
    load_lds16(Bponly + (size_t)sr0*K       + (kt)*32 + scw, &L[(bb)*12288 + 8192 + tid*8]); \
  } while(0)

  STAGE(0, 0); STAGE(1, 1);
  asm volatile("s_waitcnt vmcnt(3)" ::: "memory");
  hard_barrier();

  const int rchunk = ((lg ^ ((l15 >> 1) & 3)) << 3);

  int bt = 0;
  for (int t = 0; t < nk; ++t){
    const short* Ab = &L[bt*12288];
    const short* Bb = &L[bt*12288 + 8192];
    frag_ab af[4], bf[4];
    #pragma unroll
    for (int m=0;m<4;m++) af[m] = *(const frag_ab*)&Ab[(wr*64 + m*16 + l15)*32 + rchunk];
    #pragma unroll
    for (int n=0;n<4;n++) bf[n] = *(const frag_ab*)&Bb[(wc*64 + n*16 + l15)*32 + rchunk];
    if (t + 2 < nk){
      int bs = bt + 2; if (bs >= 3) bs -= 3;
      STAGE(t+2, bs);
    }
    __builtin_amdgcn_s_setprio(1);
    #pragma unroll
    for (int m=0;m<4;m++)
      #pragma unroll
      for (int n=0;n<4;n++)
        acc[m][n] = __builtin_amdgcn_mfma_f32_16x16x32_bf16(af[m], bf[n], acc[m][n], 0, 0, 0);
    __builtin_amdgcn_s_setprio(0);
    if (t < nk-2) asm volatile("s_waitcnt vmcnt(3)" ::: "memory");
    else          asm volatile("s_waitcnt vmcnt(0)" ::: "memory");
    hard_barrier();
    bt = (bt == 2) ? 0 : bt + 1;
  }
  #undef STAGE

  #pragma unroll
  for (int m=0;m<4;m++)
    #pragma unroll
    for (int n=0;n<4;n++)
      #pragma unroll
      for (int r=0;r<4;r++){
        size_t row = brow + wr*64 + m*16 + lg*4 + r;
        size_t col = bcol + wc*64 + n*16 + l15;
        float v = acc[m][n][r];
        if constexpr (sizeof(OutT) == 4) C[row*(size_t)N + col] = v;
        else                             C[row*(size_t)N + col] = f2bf(v);
      }
}

// ---------------- RoPE in-place on QKV (Q heads + K heads) ----------------
__global__ __launch_bounds__(256) void k_rope(short* __restrict__ QKV, const int* __restrict__ pos){
  int idx = blockIdx.x*256 + threadIdx.x;     // total = 2048 * 40 * 64
  int j   = idx & 63;
  int hh  = (idx >> 6) % 40;
  int row = (idx >> 6) / 40;
  int colbase = hh < NH ? hh*HD : HIDDEN + (hh-NH)*HD;
  size_t base = (size_t)row*QKVC + colbase;
  float x1 = bf2f(QKV[base + j]), x2 = bf2f(QKV[base + j + 64]);
  float ang = (float)pos[row] * exp2f(-(float)j * 0.2076205059304601f); // log2(1e4)/64
  float sn, cs; sincosf(ang, &sn, &cs);
  QKV[base + j]      = f2bf(x1*cs - x2*sn);
  QKV[base + j + 64] = f2bf(x2*cs + x1*sn);
}

// --------- attn staging: K (row-XOR-swizzled) + V^T (chunk-XOR-swizzled), all gload_lds ---------
__device__ __forceinline__ void astage(const short* __restrict__ QKV, const short* __restrict__ VT,
                                       short* KsB, short* VsB, int kt, int tid, int kvh){
  #pragma unroll
  for (int i=0;i<2;i++){
    int s = tid + i*256;                 // 512 chunks of 16B: K tile 32 x 128
    int r = s >> 4, c = (s & 15) << 3;
    load_lds16(QKV + (size_t)(kt*32 + r)*QKVC + HIDDEN + kvh*HD + (c ^ ((r & 7) << 3)), &KsB[s*8]);
  }
  #pragma unroll
  for (int i=0;i<2;i++){
    int s = tid + i*256;                 // 512 chunks of 16B: V^T tile 128 x 32
    int r = s >> 2, cw = ((s & 3) ^ ((s >> 3) & 3)) << 3;
    load_lds16(VT + (size_t)(kvh*HD + r)*2048 + kt*32 + cw, &VsB[s*8]);
  }
}

// ---------------- flash attention (swapped-operand softmax, q lane-local) ----------------
// block = (pair of q-tiles {qt, 31-qt}, 1 head); S^T = mfma(K,Q) so each lane owns one q-row.
__global__ __launch_bounds__(256) void k_attn(const short* __restrict__ QKV, const short* __restrict__ VT,
                                              short* __restrict__ Attn){
  const int pairI = blockIdx.x, h = blockIdx.y, kvh = h >> 2;
  const int tid = threadIdx.x, lane = tid & 63, w = tid >> 6;
  const int l15 = lane & 15, lg = lane >> 4;
  __shared__ __align__(16) short Ks[2][32*128];   // K double-buffer
  __shared__ __align__(16) short Vs[2][128*32];   // V^T double-buffer (chunk-swizzled)
  __shared__ __align__(16) short Ps[4][16*40];    // per-wave P^T tile [q=16][k=32], stride 40

  const float SC = 0.08838834764831845f;  // 1/sqrt(128)
  const int vchunk = ((l15 >> 1) & 3);    // V read swizzle (row = df*16+l15)

  for (int half = 0; half < 2; ++half){
    const int qt = half ? (31 - pairI) : pairI;
    const int q_abs = qt*64 + w*16 + l15;
    // Q fragments (16 rows per wave) from global, held in registers
    frag_ab aq[4];
    {
      const short* qrow = QKV + (size_t)q_abs*QKVC + h*HD;
      #pragma unroll
      for (int ks=0;ks<4;ks++) aq[ks] = *(const frag_ab*)&qrow[ks*32 + lg*8];
    }
    float m = -INFINITY, l = 0.f;
    f32x4 o[8] = {};
    const int nkv = 2*qt + 2;   // >= 2 always

    astage(QKV, VT, Ks[0], Vs[0], 0, tid, kvh);
    astage(QKV, VT, Ks[1], Vs[1], 1, tid, kvh);
    asm volatile("s_waitcnt vmcnt(4)" ::: "memory");
    hard_barrier();

    int bt = 0;
    for (int kt = 0; kt < nkv; ++kt){
      // S^T = mfma(K, Q): lane holds q = l15, k = frag*16 + lg*4 + r
      f32x4 st[2] = {};
      __builtin_amdgcn_s_setprio(1);
      #pragma unroll
      for (int ks=0;ks<4;ks++){
        int c = ks*32 + lg*8;
        frag_ab b0 = *(const frag_ab*)&Ks[bt][l15*128      + (c ^ ((l15 & 7) << 3))];
        frag_ab b1 = *(const frag_ab*)&Ks[bt][(16+l15)*128 + (c ^ ((l15 & 7) << 3))];
        st[0] = __builtin_amdgcn_mfma_f32_16x16x32_bf16(b0, aq[ks], st[0], 0, 0, 0);
        st[1] = __builtin_amdgcn_mfma_f32_16x16x32_bf16(b1, aq[ks], st[1], 0, 0, 0);
      }
      __builtin_amdgcn_s_setprio(0);
      // mask (k_abs > q_abs) on raw scores
      const int kb = kt*32 + lg*4;
      float v0[4], v1[4];
      #pragma unroll
      for (int r=0;r<4;r++){
        v0[r] = (kb + r      > q_abs) ? -1e30f : st[0][r];
        v1[r] = (kb + 16 + r > q_abs) ? -1e30f : st[1][r];
      }
      // row max: 7 in-lane + 2 shfl (lanes sharing l15)
      float M = fmaxf(fmaxf(fmaxf(v0[0],v0[1]),fmaxf(v0[2],v0[3])),
                      fmaxf(fmaxf(v1[0],v1[1]),fmaxf(v1[2],v1[3])));
      M = fmaxf(M, __shfl_xor(M, 16));
      M = fmaxf(M, __shfl_xor(M, 32));
      float mn = fmaxf(m, M*SC);
      float f  = __expf(m - mn);
      float p0[4], p1[4], ps = 0.f;
      #pragma unroll
      for (int r=0;r<4;r++){
        p0[r] = __expf(fmaf(v0[r], SC, -mn));
        p1[r] = __expf(fmaf(v1[r], SC, -mn));
        ps += p0[r] + p1[r];
      }
      ps += __shfl_xor(ps, 16);
      ps += __shfl_xor(ps, 32);
      l = l*f + ps;
      m = mn;
      // rescale O (uniform f per lane)
      #pragma unroll
      for (int df=0;df<8;df++)
        #pragma unroll
        for (int r=0;r<4;r++) o[df][r] *= f;
      // P^T -> Ps: row q=l15, k chunks [lg*4..+3] and [16+lg*4..+3], two b64 writes
      short4 w0, w1;
      w0.x=f2bf(p0[0]); w0.y=f2bf(p0[1]); w0.z=f2bf(p0[2]); w0.w=f2bf(p0[3]);
      w1.x=f2bf(p1[0]); w1.y=f2bf(p1[1]); w1.z=f2bf(p1[2]); w1.w=f2bf(p1[3]);
      *(short4*)&Ps[w][l15*40 + lg*4]      = w0;
      *(short4*)&Ps[w][l15*40 + 16 + lg*4] = w1;
      // O^T += mfma(V^T, P^T): lane holds q = l15, d = df*16 + lg*4 + r
      frag_ab pa = *(const frag_ab*)&Ps[w][l15*40 + lg*8];
      __builtin_amdgcn_s_setprio(1);
      #pragma unroll
      for (int df=0;df<8;df++){
        frag_ab vb = *(const frag_ab*)&Vs[bt][(df*16+l15)*32 + ((lg ^ vchunk) << 3)];
        o[df] = __builtin_amdgcn_mfma_f32_16x16x32_bf16(vb, pa, o[df], 0, 0, 0);
      }
      __builtin_amdgcn_s_setprio(0);
      hard_barrier();                       // all waves done reading buffer bt
      if (kt + 2 < nkv){
        astage(QKV, VT, Ks[bt], Vs[bt], kt+2, tid, kvh);
        asm volatile("s_waitcnt vmcnt(4)" ::: "memory");   // tile kt+1 landed
        hard_barrier();
      } else if (kt + 1 < nkv){
        asm volatile("s_waitcnt vmcnt(0)" ::: "memory");
        hard_barrier();
      }
      bt ^= 1;
    }
    // epilogue: O^T/l -> Attn[q][h*128 + d], packed 4 consecutive d per store
    float inv = 1.0f / l;
    #pragma unroll
    for (int df=0;df<8;df++){
      short4 s4;
      s4.x = f2bf(o[df][0]*inv); s4.y = f2bf(o[df][1]*inv);
      s4.z = f2bf(o[df][2]*inv); s4.w = f2bf(o[df][3]*inv);
      *(short4*)&Attn[(size_t)q_abs*HIDDEN + h*HD + df*16 + lg*4] = s4;
    }
  }
}

// ---------------- launch ----------------
extern "C" void kernel_launch(void* const* d_in, const int* in_sizes, int n_in,
                              void* d_out, int out_size, void* d_ws, size_t ws_size,
                              hipStream_t stream) {
  const float* H  = (const float*)d_in[0];
  const int*  pos = (const int*)  d_in[1];
  const float* Wq = (const float*)d_in[2];
  const float* Wk = (const float*)d_in[3];
  const float* Wv = (const float*)d_in[4];
  const float* Wo = (const float*)d_in[5];
  float* out = (float*)d_out;

  char* ws = (char*)d_ws;
  short* WT   = (short*)(ws);                       // [6144][4096] bf16 (Wq^T | Wk^T | Wv^T)
  short* WoT  = (short*)(ws + 50331648);            // [4096][4096] bf16
  short* Hb   = (short*)(ws + 83886080);            // [2048][4096] bf16 (dead after QKV GEMM)
  short* QKV  = (short*)(ws + 100663296);           // [2048][6144] bf16
  short* Attn = (short*)(ws + 125829120);           // [2048][4096] bf16
  short* VT   = Hb;                                 // [1024][2048] bf16 (reuses Hb slot)

  k_cvt<<<8192, 256, 0, stream>>>(H, Hb, 2097152);
  k_transpose<<<dim3(128,128), 256, 0, stream>>>(Wq, WT,                        4096, 4096);
  k_transpose<<<dim3( 32,128), 256, 0, stream>>>(Wk, WT + (size_t)4096*4096,    4096, 1024);
  k_transpose<<<dim3( 32,128), 256, 0, stream>>>(Wv, WT + (size_t)5120*4096,    4096, 1024);
  k_transpose<<<dim3(128,128), 256, 0, stream>>>(Wo, WoT,                       4096, 4096);

  // QKV GEMM: M=2048 (8 tiles), N=6144 (48 tiles) -> 384 blocks (%8==0)
  k_gemm256<short><<<384, 512, 0, stream>>>(Hb, WT, QKV, 2048, 6144, 4096, 8);
  k_rope<<<20480, 256, 0, stream>>>(QKV, pos);
  k_transpose_v<<<dim3(64,32), 256, 0, stream>>>(QKV, VT);
  k_attn<<<dim3(16,32), 256, 0, stream>>>(QKV, VT, Attn);
  // Out-proj: M=2048 (8 tiles), N=4096 (32 tiles) -> 256 blocks (%8==0)
  k_gemm256<float><<<256, 512, 0, stream>>>(Attn, WoT, out, 2048, 4096, 4096, 8);
}